// Round 6
// baseline (300.347 us; speedup 1.0000x reference)
//
#include <hip/hip_runtime.h>
#include <hip/hip_bf16.h>
#include <math.h>

#define B_ 4
#define S_ 2048
#define D_ 512
#define H_ 8
#define DK_ 64
#define DFF_ 2048
#define NEG_ (-1.0e9f)
#define EPS_ 1e-6f
#define LOG2E_ 1.4426950408889634f

typedef __attribute__((ext_vector_type(8))) short bf16x8;
typedef __attribute__((ext_vector_type(4))) float f32x4;

__device__ inline unsigned short f2bf(float f) {
    unsigned u = __float_as_uint(f);
    unsigned r = u + 0x7FFFu + ((u >> 16) & 1u);
    return (unsigned short)(r >> 16);
}

// packed pair f32->bf16 (RNE) -> one u32; compiler emits v_cvt_pk_bf16_f32
__device__ inline unsigned int packbf2(float a, float b) {
    __hip_bfloat162 h = __float22bfloat162_rn(float2{a, b});
    unsigned int u;
    __builtin_memcpy(&u, &h, 4);
    return u;
}

__device__ inline f32x4 mfma16(bf16x8 a, bf16x8 b, f32x4 c) {
    return __builtin_amdgcn_mfma_f32_16x16x32_bf16(a, b, c, 0, 0, 0);
}

// global -> LDS direct, 16B per lane. LDS dest = wave-uniform base + lane*16.
__device__ inline void gload16(const void* g, void* l) {
    __builtin_amdgcn_global_load_lds(
        (const __attribute__((address_space(1))) unsigned int*)g,
        (__attribute__((address_space(3))) unsigned int*)l, 16, 0, 0);
}

// ---------------------------------------------------------------------------
// Mask canonicalization -> additive f32 bias (0 or NEG). Handles u8 / 4-byte.
// ---------------------------------------------------------------------------
__global__ void mask_canon_kernel(const unsigned char* __restrict__ mraw,
                                  float* __restrict__ mb) {
    __shared__ int s_bad;
    int tid = threadIdx.x;
    if (tid == 0) s_bad = 0;
    __syncthreads();
    const unsigned int* w = (const unsigned int*)mraw;
    int bad = 0;
    for (int i = tid; i < (B_ * S_) / 4; i += 256) {
        unsigned int v = w[i];
        if (!(v == 0u || v == 1u || v == 0x3F800000u)) bad = 1;
    }
    if (bad) atomicOr(&s_bad, 1);
    __syncthreads();
    int i = blockIdx.x * 256 + tid;
    if (s_bad) {  // u8 layout
        for (; i < B_ * S_; i += 2048) mb[i] = mraw[i] ? NEG_ : 0.f;
    } else {      // 4-byte layout
        for (; i < B_ * S_; i += 2048) mb[i] = w[i] ? NEG_ : 0.f;
    }
}

// ---------------------------------------------------------------------------
// One-shot f32 -> bf16 conversion of x + all weights. wq scaled by
// 0.125*log2(e): folds both the 1/sqrt(DK) attn scale and the exp->exp2
// conversion into Q.
// ---------------------------------------------------------------------------
__global__ __launch_bounds__(256) void convert_all_kernel(
    const float* __restrict__ x,  const float* __restrict__ wq,
    const float* __restrict__ wk, const float* __restrict__ wv,
    const float* __restrict__ wo, const float* __restrict__ w1,
    const float* __restrict__ w2,
    unsigned short* __restrict__ xb, unsigned short* __restrict__ wqkvb,
    unsigned short* __restrict__ wob, unsigned short* __restrict__ w1b,
    unsigned short* __restrict__ w2b)
{
    int i = blockIdx.x * 256 + threadIdx.x;   // float4 index, total 1835008
    const float* src; unsigned short* dst; int off; float s = 1.f;
    if (i < 1048576)      { src = x;  dst = xb;             off = i;           }
    else if (i < 1114112) { src = wq; dst = wqkvb;          off = i - 1048576; s = 0.125f * LOG2E_; }
    else if (i < 1179648) { src = wk; dst = wqkvb + 262144; off = i - 1114112; }
    else if (i < 1245184) { src = wv; dst = wqkvb + 524288; off = i - 1179648; }
    else if (i < 1310720) { src = wo; dst = wob;            off = i - 1245184; }
    else if (i < 1572864) { src = w1; dst = w1b;            off = i - 1310720; }
    else                  { src = w2; dst = w2b;            off = i - 1572864; }
    float4 v = reinterpret_cast<const float4*>(src)[off];
    ushort4 o;
    o.x = f2bf(v.x * s); o.y = f2bf(v.y * s); o.z = f2bf(v.z * s); o.w = f2bf(v.w * s);
    reinterpret_cast<ushort4*>(dst)[off] = o;
}

// ---------------------------------------------------------------------------
// Generic MFMA GEMM: C[M,N] = A[M,K](bf16) @ W[N,K](bf16)^T + bias(f32)
// XCD-aware bijective block remap: each XCD owns a contiguous chunk of
// m-panels (all n) so A-panels + W stay resident in its private L2.
// ---------------------------------------------------------------------------
template<int BM, int BN, bool RELU, bool OUT_BF16>
__global__ __launch_bounds__(256) void gemm_mfma(
    const unsigned short* __restrict__ A, const unsigned short* __restrict__ W,
    const float* __restrict__ bias, void* __restrict__ Cout,
    int M, int N, int K)
{
    constexpr int FM = BM / 32;
    constexpr int FN = BN / 32;
    __shared__ unsigned short Asl[BM * 64];
    __shared__ unsigned short Bsl[BN * 64];

    const int tid = threadIdx.x;
    const int w = tid >> 6, lane = tid & 63;
    const int lr = lane & 15, lg = lane >> 4;
    const int wm = w >> 1, wn = w & 1;
    const int gx = gridDim.x;
    const int flat = blockIdx.y * gx + blockIdx.x;
    const int cpx = (gx * gridDim.y) >> 3;      // grids are multiples of 8
    const int nf = (flat & 7) * cpx + (flat >> 3);
    const int m0 = (nf / gx) * BM, n0 = (nf % gx) * BN;
    const int srow = lane >> 3;
    const int schunk = lane & 7;

    f32x4 acc[FM][FN] = {};

    for (int k0 = 0; k0 < K; k0 += 64) {
        __syncthreads();
        #pragma unroll
        for (int j = 0; j < BM / 32; ++j) {
            int instr = w * (BM / 32) + j;
            int row = instr * 8 + srow;
            const unsigned short* src =
                A + (size_t)(m0 + row) * K + k0 + ((schunk ^ (row & 7)) * 8);
            gload16(src, &Asl[instr * 512]);
        }
        #pragma unroll
        for (int j = 0; j < BN / 32; ++j) {
            int instr = w * (BN / 32) + j;
            int row = instr * 8 + srow;
            const unsigned short* src =
                W + (size_t)(n0 + row) * K + k0 + ((schunk ^ (row & 7)) * 8);
            gload16(src, &Bsl[instr * 512]);
        }
        __syncthreads();

        bf16x8 af[FM][2], bfr[FN][2];
        #pragma unroll
        for (int m = 0; m < FM; ++m)
            #pragma unroll
            for (int ko = 0; ko < 2; ++ko) {
                int row = wm * (FM * 16) + m * 16 + lr;
                int slot = (lg + 4 * ko) ^ (row & 7);
                af[m][ko] = *(const bf16x8*)&Asl[row * 64 + slot * 8];
            }
        #pragma unroll
        for (int n = 0; n < FN; ++n)
            #pragma unroll
            for (int ko = 0; ko < 2; ++ko) {
                int row = wn * (FN * 16) + n * 16 + lr;
                int slot = (lg + 4 * ko) ^ (row & 7);
                bfr[n][ko] = *(const bf16x8*)&Bsl[row * 64 + slot * 8];
            }
        #pragma unroll
        for (int m = 0; m < FM; ++m)
            #pragma unroll
            for (int n = 0; n < FN; ++n)
                #pragma unroll
                for (int ko = 0; ko < 2; ++ko)
                    acc[m][n] = mfma16(af[m][ko], bfr[n][ko], acc[m][n]);
    }

    #pragma unroll
    for (int n = 0; n < FN; ++n) {
        int col = n0 + wn * (FN * 16) + n * 16 + lr;
        float bv = bias[col];
        #pragma unroll
        for (int m = 0; m < FM; ++m) {
            int rowb = m0 + wm * (FM * 16) + m * 16 + lg * 4;
            #pragma unroll
            for (int r = 0; r < 4; ++r) {
                float v = acc[m][n][r] + bv;
                if (RELU) v = fmaxf(v, 0.f);
                if (OUT_BF16)
                    ((unsigned short*)Cout)[(size_t)(rowb + r) * N + col] = f2bf(v);
                else
                    ((float*)Cout)[(size_t)(rowb + r) * N + col] = v;
            }
        }
    }
}

// ---------------------------------------------------------------------------
// QKV GEMM: A[8192,512] @ Wqkv[1536,512]^T + bias (gathered from bq/bk/bv).
// Cols [0,1024) -> QKb [8192][1024] (Q|K packed; Q pre-scaled by .125*log2e).
// Cols [1024,1536) -> VT [b][h][d=64][s=2048] bf16, packed ushort4 along s.
// ---------------------------------------------------------------------------
__global__ __launch_bounds__(256) void gemm_qkv(
    const unsigned short* __restrict__ A, const unsigned short* __restrict__ W,
    const float* __restrict__ bqp, const float* __restrict__ bkp,
    const float* __restrict__ bvp, unsigned short* __restrict__ QKb,
    unsigned short* __restrict__ VTg)
{
    constexpr int K = 512;
    __shared__ unsigned short Asl[128 * 64];
    __shared__ unsigned short Bsl[128 * 64];

    const int tid = threadIdx.x;
    const int w = tid >> 6, lane = tid & 63;
    const int lr = lane & 15, lg = lane >> 4;
    const int wm = w >> 1, wn = w & 1;
    const int flat = blockIdx.y * 12 + blockIdx.x;      // grid 12 x 64 = 768
    const int nf = (flat & 7) * 96 + (flat >> 3);
    const int m0 = (nf / 12) * 128, n0 = (nf % 12) * 128;
    const int srow = lane >> 3;
    const int schunk = lane & 7;

    f32x4 acc[4][4] = {};

    for (int k0 = 0; k0 < K; k0 += 64) {
        __syncthreads();
        #pragma unroll
        for (int j = 0; j < 4; ++j) {
            int instr = w * 4 + j;
            int row = instr * 8 + srow;
            gload16(A + (size_t)(m0 + row) * K + k0 + ((schunk ^ (row & 7)) * 8),
                    &Asl[instr * 512]);
            gload16(W + (size_t)(n0 + row) * K + k0 + ((schunk ^ (row & 7)) * 8),
                    &Bsl[instr * 512]);
        }
        __syncthreads();

        bf16x8 af[4][2], bfr[4][2];
        #pragma unroll
        for (int m = 0; m < 4; ++m)
            #pragma unroll
            for (int ko = 0; ko < 2; ++ko) {
                int row = wm * 64 + m * 16 + lr;
                int slot = (lg + 4 * ko) ^ (row & 7);
                af[m][ko] = *(const bf16x8*)&Asl[row * 64 + slot * 8];
            }
        #pragma unroll
        for (int n = 0; n < 4; ++n)
            #pragma unroll
            for (int ko = 0; ko < 2; ++ko) {
                int row = wn * 64 + n * 16 + lr;
                int slot = (lg + 4 * ko) ^ (row & 7);
                bfr[n][ko] = *(const bf16x8*)&Bsl[row * 64 + slot * 8];
            }
        #pragma unroll
        for (int m = 0; m < 4; ++m)
            #pragma unroll
            for (int n = 0; n < 4; ++n)
                #pragma unroll
                for (int ko = 0; ko < 2; ++ko)
                    acc[m][n] = mfma16(af[m][ko], bfr[n][ko], acc[m][n]);
    }

    if (n0 < 1024) {
        #pragma unroll
        for (int n = 0; n < 4; ++n) {
            int col = n0 + wn * 64 + n * 16 + lr;
            float bv = (col < 512) ? bqp[col] * (0.125f * LOG2E_) : bkp[col - 512];
            #pragma unroll
            for (int m = 0; m < 4; ++m) {
                int rowb = m0 + wm * 64 + m * 16 + lg * 4;
                #pragma unroll
                for (int r = 0; r < 4; ++r)
                    QKb[(size_t)(rowb + r) * 1024 + col] = f2bf(acc[m][n][r] + bv);
            }
        }
    } else {
        #pragma unroll
        for (int n = 0; n < 4; ++n) {
            int col = n0 + wn * 64 + n * 16 + lr;
            int dfull = col - 1024;
            int hh = dfull >> 6, dd = dfull & 63;
            float bv = bvp[dfull];
            #pragma unroll
            for (int m = 0; m < 4; ++m) {
                int rowb = m0 + wm * 64 + m * 16 + lg * 4;
                int bb = rowb >> 11;
                int s = rowb & 2047;
                ushort4 pk;
                pk.x = f2bf(acc[m][n][0] + bv);
                pk.y = f2bf(acc[m][n][1] + bv);
                pk.z = f2bf(acc[m][n][2] + bv);
                pk.w = f2bf(acc[m][n][3] + bv);
                *(ushort4*)&VTg[(((size_t)bb * 8 + hh) * 64 + dd) * 2048 + s] = pk;
            }
        }
    }
}

// ---------------------------------------------------------------------------
// stage one 64-kv K + V^T tile (wave w stages rows [16w,16w+16))
// ---------------------------------------------------------------------------
__device__ inline void stage_kv(const unsigned short* __restrict__ QKb,
                                const unsigned short* __restrict__ VTg,
                                unsigned short* ksDst, unsigned short* vtDst,
                                int b, int bh, int h, int kv0,
                                int w, int srow, int sc_x) {
    #pragma unroll
    for (int j = 0; j < 2; ++j) {
        int rl = w * 16 + j * 8 + srow;
        gload16(QKb + (size_t)(b * S_ + kv0 + rl) * 1024 + 512 + h * 64 + sc_x * 8,
                ksDst + (w * 2 + j) * 512);
        gload16(VTg + ((size_t)bh * 64 + rl) * 2048 + kv0 + sc_x * 8,
                vtDst + (w * 2 + j) * 512);
    }
}

// ---------------------------------------------------------------------------
// MFMA flash attention v5: 2-phase pipelined staging (dbuf K/VT, stage next
// tile before computing current, ONE __syncthreads per tile), exp2-domain
// softmax (log2e folded into Q), packed cvt_pk P-store, per-lane mask loads.
// QBLK=64, 1024 blocks, bijective XCD remap (KV L2-resident per XCD).
// ---------------------------------------------------------------------------
__global__ __launch_bounds__(256, 4) void attn_mfma4(
    const unsigned short* __restrict__ QKb, const unsigned short* __restrict__ VTg,
    const float* __restrict__ mb, unsigned short* __restrict__ Ob)
{
    __shared__ unsigned short Ks[2][64 * 64];   // [kv][d] swizzled, dbuf
    __shared__ unsigned short VTs[2][64 * 64];  // [d][kv] swizzled, dbuf
    __shared__ unsigned short Ps[4 * 16 * 64];  // per-wave [q][kv] swizzled
    // 16 + 16 + 8 = 40 KB -> 4 blocks/CU exactly

    const int tid = threadIdx.x;
    const int w = tid >> 6, lane = tid & 63;
    const int lr = lane & 15, lg = lane >> 4;
    const int flat = blockIdx.x + 32 * (blockIdx.y + 8 * blockIdx.z);
    const int nf = (flat & 7) * 128 + (flat >> 3);
    const int q0 = (nf & 31) * 64;
    const int bh = nf >> 5;
    const int h = bh & 7, b = bh >> 3;
    const int srow = lane >> 3;
    const int sc_x = (lane & 7) ^ srow;
    unsigned short* PsW = &Ps[w * 1024];

    // Q fragments (pre-scaled by 0.125*log2e upstream)
    bf16x8 qf[2];
    #pragma unroll
    for (int ko = 0; ko < 2; ++ko)
        qf[ko] = *(const bf16x8*)(QKb +
            (size_t)(b * S_ + q0 + w * 16 + lr) * 1024 + h * 64 + ko * 32 + lg * 8);

    f32x4 od[4] = {};
    float m_run = -INFINITY;   // log2 domain
    float l_run = 0.f;

    stage_kv(QKb, VTg, Ks[0], VTs[0], b, bh, h, 0, w, srow, sc_x);
    __syncthreads();

    int cur = 0;
    for (int kv0 = 0; kv0 < S_; kv0 += 64) {
        if (kv0 + 64 < S_)
            stage_kv(QKb, VTg, Ks[cur ^ 1], VTs[cur ^ 1], b, bh, h, kv0 + 64,
                     w, srow, sc_x);

        // per-lane mask bias loads (L1/L2-cached)
        f32x4 mbr[4];
        #pragma unroll
        for (int n = 0; n < 4; ++n)
            mbr[n] = *(const f32x4*)&mb[(size_t)b * S_ + kv0 + n * 16 + lg * 4];

        // swapped QK^T: st[n] reg r = S2[kv=16n+4lg+r][q=lr] (log2 scaled)
        f32x4 st[4] = {};
        #pragma unroll
        for (int ko = 0; ko < 2; ++ko)
            #pragma unroll
            for (int n = 0; n < 4; ++n) {
                bf16x8 kf = *(const bf16x8*)
                    &Ks[cur][(n * 16 + lr) * 64 + (((lg + 4 * ko) ^ (lr & 7)) * 8)];
                st[n] = mfma16(kf, qf[ko], st[n]);
            }

        float mtp = -INFINITY;
        #pragma unroll
        for (int n = 0; n < 4; ++n)
            #pragma unroll
            for (int r = 0; r < 4; ++r) {
                float v = st[n][r] + mbr[n][r];
                st[n][r] = v;
                mtp = fmaxf(mtp, v);
            }

        // defer-max: rescale only if partial max exceeds m_run + 8 (log2)
        if (__any(mtp > m_run + 8.f)) {
            float mt = mtp;
            mt = fmaxf(mt, __shfl_xor(mt, 16));
            mt = fmaxf(mt, __shfl_xor(mt, 32));
            float mnew = fmaxf(m_run, mt);
            float scl = exp2f(m_run - mnew);
            m_run = mnew;
            l_run *= scl;
            #pragma unroll
            for (int r = 0; r < 4; ++r) {
                float sr = __shfl(scl, lg * 4 + r);
                #pragma unroll
                for (int nd = 0; nd < 4; ++nd) od[nd][r] *= sr;
            }
        }

        float psum = 0.f;
        #pragma unroll
        for (int n = 0; n < 4; ++n) {
            float p0 = exp2f(st[n][0] - m_run);
            float p1 = exp2f(st[n][1] - m_run);
            float p2 = exp2f(st[n][2] - m_run);
            float p3 = exp2f(st[n][3] - m_run);
            psum += (p0 + p1) + (p2 + p3);
            uint2 pk;
            pk.x = packbf2(p0, p1);
            pk.y = packbf2(p2, p3);
            int chunk = (2 * n + (lg >> 1)) ^ (lr & 7);
            *(uint2*)&PsW[lr * 64 + chunk * 8 + (lg & 1) * 4] = pk;
        }
        psum += __shfl_xor(psum, 16);
        psum += __shfl_xor(psum, 32);
        l_run += psum;

        // PV: od[nd] += P[q][kv] * V^T[d][kv]
        #pragma unroll
        for (int ko = 0; ko < 2; ++ko) {
            int slotx = ((lg + 4 * ko) ^ (lr & 7)) * 8;
            bf16x8 pa = *(const bf16x8*)&PsW[lr * 64 + slotx];
            #pragma unroll
            for (int nd = 0; nd < 4; ++nd) {
                bf16x8 vf = *(const bf16x8*)&VTs[cur][(nd * 16 + lr) * 64 + slotx];
                od[nd] = mfma16(pa, vf, od[nd]);
            }
        }
        __syncthreads();   // drains stage loads (hidden under compute above)
        cur ^= 1;
    }

    float linv = 1.f / l_run;
    #pragma unroll
    for (int r = 0; r < 4; ++r) {
        float iv = __shfl(linv, lg * 4 + r);
        size_t row = (size_t)(b * S_ + q0 + w * 16 + lg * 4 + r);
        #pragma unroll
        for (int nd = 0; nd < 4; ++nd)
            Ob[row * 512 + h * 64 + nd * 16 + lr] = f2bf(od[nd][r] * iv);
    }
}

// ---------------------------------------------------------------------------
// y = x + gamma*(a-mean)/sqrt(var_ddof1+eps) + beta ; optional bf16 copy of y
// ---------------------------------------------------------------------------
__global__ __launch_bounds__(256) void add_ln_kernel(
    const float* __restrict__ x, const float* __restrict__ a,
    const float* __restrict__ g, const float* __restrict__ beta,
    float* __restrict__ y, unsigned short* __restrict__ ybf)
{
    int rowid = blockIdx.x;
    int tid = threadIdx.x;
    const float2 a2 = reinterpret_cast<const float2*>(a + (size_t)rowid * D_)[tid];
    float s = a2.x + a2.y;
    float ss = a2.x * a2.x + a2.y * a2.y;
    #pragma unroll
    for (int off = 32; off > 0; off >>= 1) {
        s += __shfl_down(s, off);
        ss += __shfl_down(ss, off);
    }
    __shared__ float ws_s[4], ws_ss[4];
    __shared__ float s_mean, s_rstd;
    int wave = tid >> 6, lane = tid & 63;
    if (lane == 0) { ws_s[wave] = s; ws_ss[wave] = ss; }
    __syncthreads();
    if (tid == 0) {
        float st = ws_s[0] + ws_s[1] + ws_s[2] + ws_s[3];
        float sst = ws_ss[0] + ws_ss[1] + ws_ss[2] + ws_ss[3];
        float mean = st / (float)D_;
        float var = (sst - (float)D_ * mean * mean) / (float)(D_ - 1);
        s_mean = mean;
        s_rstd = rsqrtf(var + EPS_);
    }
    __syncthreads();
    float mean = s_mean, rstd = s_rstd, gg = g[0], bb = beta[0];
    const float2 x2 = reinterpret_cast<const float2*>(x + (size_t)rowid * D_)[tid];
    float2 o;
    o.x = x2.x + gg * (a2.x - mean) * rstd + bb;
    o.y = x2.y + gg * (a2.y - mean) * rstd + bb;
    reinterpret_cast<float2*>(y + (size_t)rowid * D_)[tid] = o;
    if (ybf) {
        ushort2 ob; ob.x = f2bf(o.x); ob.y = f2bf(o.y);
        reinterpret_cast<ushort2*>(ybf + (size_t)rowid * D_)[tid] = ob;
    }
}

// ---------------------------------------------------------------------------
extern "C" void kernel_launch(void* const* d_in, const int* in_sizes, int n_in,
                              void* d_out, int out_size, void* d_ws, size_t ws_size,
                              hipStream_t stream) {
    const float* x  = (const float*)d_in[0];
    const unsigned char* mask = (const unsigned char*)d_in[1];
    const float* wq = (const float*)d_in[2];
    const float* bq = (const float*)d_in[3];
    const float* wk = (const float*)d_in[4];
    const float* bk = (const float*)d_in[5];
    const float* wv = (const float*)d_in[6];
    const float* bv = (const float*)d_in[7];
    const float* wo = (const float*)d_in[8];
    const float* bo = (const float*)d_in[9];
    const float* w1 = (const float*)d_in[10];
    const float* b1 = (const float*)d_in[11];
    const float* w2 = (const float*)d_in[12];
    const float* b2 = (const float*)d_in[13];
    const float* g1 = (const float*)d_in[14];
    const float* be1 = (const float*)d_in[15];
    const float* g2 = (const float*)d_in[16];
    const float* be2 = (const float*)d_in[17];
    float* out = (float*)d_out;
    char* base = (char*)d_ws;

    const size_t MS = (size_t)B_ * S_;                              // 8192
    unsigned short* QKb  = (unsigned short*)(base);                 // 16 MB
    unsigned short* VTg  = (unsigned short*)(base + 16777216);      // 8 MB
    unsigned short* Ob   = (unsigned short*)(base + 25165824);      // 8 MB
    unsigned short* ff1  = (unsigned short*)(base);                 // 32 MB overlay
    float*          att  = (float*)(base + 33554432);               // 16 MB
    float*          ff2  = att;                                     // overlay
    float*          y    = (float*)(base + 50331648);               // 16 MB
    unsigned short* ybf  = (unsigned short*)(base + 67108864);      // 8 MB
    unsigned short* xb   = (unsigned short*)(base + 75497472);      // 8 MB
    unsigned short* wqkvb= (unsigned short*)(base + 83886080);      // 1.5 MB
    unsigned short* wob  = (unsigned short*)(base + 85458944);      // 0.5 MB
    unsigned short* w1b  = (unsigned short*)(base + 85983232);      // 2 MB
    unsigned short* w2b  = (unsigned short*)(base + 88080384);      // 2 MB
    float*          mbv  = (float*)(base + 90183680);               // 32 KB

    dim3 blk(256);
    mask_canon_kernel<<<8, blk, 0, stream>>>(mask, mbv);

    convert_all_kernel<<<7168, blk, 0, stream>>>(
        x, wq, wk, wv, wo, w1, w2, xb, wqkvb, wob, w1b, w2b);

    // fused QKV projection; Q pre-scaled, V written transposed per-head
    gemm_qkv<<<dim3(12, MS / 128), blk, 0, stream>>>(
        xb, wqkvb, bq, bk, bv, QKb, VTg);

    attn_mfma4<<<dim3(S_ / 64, H_, B_), blk, 0, stream>>>(QKb, VTg, mbv, Ob);

    gemm_mfma<128,64,false,false><<<dim3(D_/64, MS/128), blk, 0, stream>>>(
        Ob, wob, bo, att, MS, D_, D_);

    add_ln_kernel<<<dim3((unsigned)MS), blk, 0, stream>>>(x, att, g1, be1, y, ybf);

    gemm_mfma<128,128,true,true><<<dim3(DFF_/128, MS/128), blk, 0, stream>>>(
        ybf, w1b, b1, ff1, MS, DFF_, D_);
    gemm_mfma<128,64,false,false><<<dim3(D_/64, MS/128), blk, 0, stream>>>(
        ff1, w2b, b2, ff2, MS, D_, DFF_);

    add_ln_kernel<<<dim3((unsigned)MS), blk, 0, stream>>>(y, ff2, g2, be2, out, nullptr);
}

// Round 7
// 296.077 us; speedup vs baseline: 1.0144x; 1.0144x over previous
//
#include <hip/hip_runtime.h>
#include <hip/hip_bf16.h>
#include <math.h>

#define B_ 4
#define S_ 2048
#define D_ 512
#define H_ 8
#define DK_ 64
#define DFF_ 2048
#define NEG_ (-1.0e9f)
#define EPS_ 1e-6f
#define LOG2E_ 1.4426950408889634f

typedef __attribute__((ext_vector_type(8))) short bf16x8;
typedef __attribute__((ext_vector_type(4))) float f32x4;

__device__ inline unsigned short f2bf(float f) {
    unsigned u = __float_as_uint(f);
    unsigned r = u + 0x7FFFu + ((u >> 16) & 1u);
    return (unsigned short)(r >> 16);
}

__device__ inline f32x4 mfma16(bf16x8 a, bf16x8 b, f32x4 c) {
    return __builtin_amdgcn_mfma_f32_16x16x32_bf16(a, b, c, 0, 0, 0);
}

// global -> LDS direct. LDS dest = wave-uniform base + lane*size.
__device__ inline void gload16(const void* g, void* l) {
    __builtin_amdgcn_global_load_lds(
        (const __attribute__((address_space(1))) unsigned int*)g,
        (__attribute__((address_space(3))) unsigned int*)l, 16, 0, 0);
}
__device__ inline void gload4(const void* g, void* l) {
    __builtin_amdgcn_global_load_lds(
        (const __attribute__((address_space(1))) unsigned int*)g,
        (__attribute__((address_space(3))) unsigned int*)l, 4, 0, 0);
}

// ---------------------------------------------------------------------------
// Merged: blocks 0..7 canonicalize mask -> additive f32 bias (0 or NEG);
// blocks 8.. convert x + weights f32->bf16 (wq/bq scale folded: 0.125*log2e).
// ---------------------------------------------------------------------------
__global__ __launch_bounds__(256) void prep_kernel(
    const unsigned char* __restrict__ mraw, float* __restrict__ mb,
    const float* __restrict__ x,  const float* __restrict__ wq,
    const float* __restrict__ wk, const float* __restrict__ wv,
    const float* __restrict__ wo, const float* __restrict__ w1,
    const float* __restrict__ w2,
    unsigned short* __restrict__ xb, unsigned short* __restrict__ wqkvb,
    unsigned short* __restrict__ wob, unsigned short* __restrict__ w1b,
    unsigned short* __restrict__ w2b)
{
    int tid = threadIdx.x;
    if (blockIdx.x < 8) {
        __shared__ int s_bad;
        if (tid == 0) s_bad = 0;
        __syncthreads();
        const unsigned int* w = (const unsigned int*)mraw;
        int bad = 0;
        for (int i = tid; i < (B_ * S_) / 4; i += 256) {
            unsigned int v = w[i];
            if (!(v == 0u || v == 1u || v == 0x3F800000u)) bad = 1;
        }
        if (bad) atomicOr(&s_bad, 1);
        __syncthreads();
        int i = blockIdx.x * 256 + tid;
        if (s_bad) {  // u8 layout
            for (; i < B_ * S_; i += 2048) mb[i] = mraw[i] ? NEG_ : 0.f;
        } else {      // 4-byte layout
            for (; i < B_ * S_; i += 2048) mb[i] = w[i] ? NEG_ : 0.f;
        }
        return;
    }
    int i = (blockIdx.x - 8) * 256 + tid;   // float4 index, total 1835008
    const float* src; unsigned short* dst; int off; float s = 1.f;
    if (i < 1048576)      { src = x;  dst = xb;             off = i;           }
    else if (i < 1114112) { src = wq; dst = wqkvb;          off = i - 1048576; s = 0.125f * LOG2E_; }
    else if (i < 1179648) { src = wk; dst = wqkvb + 262144; off = i - 1114112; }
    else if (i < 1245184) { src = wv; dst = wqkvb + 524288; off = i - 1179648; }
    else if (i < 1310720) { src = wo; dst = wob;            off = i - 1245184; }
    else if (i < 1572864) { src = w1; dst = w1b;            off = i - 1310720; }
    else                  { src = w2; dst = w2b;            off = i - 1572864; }
    float4 v = reinterpret_cast<const float4*>(src)[off];
    ushort4 o;
    o.x = f2bf(v.x * s); o.y = f2bf(v.y * s); o.z = f2bf(v.z * s); o.w = f2bf(v.w * s);
    reinterpret_cast<ushort4*>(dst)[off] = o;
}

// ---------------------------------------------------------------------------
// Generic MFMA GEMM: C[M,N] = A[M,K](bf16) @ W[N,K](bf16)^T + bias(f32)
// XCD-aware bijective block remap (grids are multiples of 8).
// ---------------------------------------------------------------------------
template<int BM, int BN, bool RELU, bool OUT_BF16>
__global__ __launch_bounds__(256) void gemm_mfma(
    const unsigned short* __restrict__ A, const unsigned short* __restrict__ W,
    const float* __restrict__ bias, void* __restrict__ Cout,
    int M, int N, int K)
{
    constexpr int FM = BM / 32;
    constexpr int FN = BN / 32;
    __shared__ unsigned short Asl[BM * 64];
    __shared__ unsigned short Bsl[BN * 64];

    const int tid = threadIdx.x;
    const int w = tid >> 6, lane = tid & 63;
    const int lr = lane & 15, lg = lane >> 4;
    const int wm = w >> 1, wn = w & 1;
    const int gx = gridDim.x;
    const int flat = blockIdx.y * gx + blockIdx.x;
    const int cpx = (gx * gridDim.y) >> 3;
    const int nf = (flat & 7) * cpx + (flat >> 3);
    const int m0 = (nf / gx) * BM, n0 = (nf % gx) * BN;
    const int srow = lane >> 3;
    const int schunk = lane & 7;

    f32x4 acc[FM][FN] = {};

    for (int k0 = 0; k0 < K; k0 += 64) {
        __syncthreads();
        #pragma unroll
        for (int j = 0; j < BM / 32; ++j) {
            int instr = w * (BM / 32) + j;
            int row = instr * 8 + srow;
            const unsigned short* src =
                A + (size_t)(m0 + row) * K + k0 + ((schunk ^ (row & 7)) * 8);
            gload16(src, &Asl[instr * 512]);
        }
        #pragma unroll
        for (int j = 0; j < BN / 32; ++j) {
            int instr = w * (BN / 32) + j;
            int row = instr * 8 + srow;
            const unsigned short* src =
                W + (size_t)(n0 + row) * K + k0 + ((schunk ^ (row & 7)) * 8);
            gload16(src, &Bsl[instr * 512]);
        }
        __syncthreads();

        bf16x8 af[FM][2], bfr[FN][2];
        #pragma unroll
        for (int m = 0; m < FM; ++m)
            #pragma unroll
            for (int ko = 0; ko < 2; ++ko) {
                int row = wm * (FM * 16) + m * 16 + lr;
                int slot = (lg + 4 * ko) ^ (row & 7);
                af[m][ko] = *(const bf16x8*)&Asl[row * 64 + slot * 8];
            }
        #pragma unroll
        for (int n = 0; n < FN; ++n)
            #pragma unroll
            for (int ko = 0; ko < 2; ++ko) {
                int row = wn * (FN * 16) + n * 16 + lr;
                int slot = (lg + 4 * ko) ^ (row & 7);
                bfr[n][ko] = *(const bf16x8*)&Bsl[row * 64 + slot * 8];
            }
        #pragma unroll
        for (int m = 0; m < FM; ++m)
            #pragma unroll
            for (int n = 0; n < FN; ++n)
                #pragma unroll
                for (int ko = 0; ko < 2; ++ko)
                    acc[m][n] = mfma16(af[m][ko], bfr[n][ko], acc[m][n]);
    }

    #pragma unroll
    for (int n = 0; n < FN; ++n) {
        int col = n0 + wn * (FN * 16) + n * 16 + lr;
        float bv = bias[col];
        #pragma unroll
        for (int m = 0; m < FM; ++m) {
            int rowb = m0 + wm * (FM * 16) + m * 16 + lg * 4;
            #pragma unroll
            for (int r = 0; r < 4; ++r) {
                float v = acc[m][n][r] + bv;
                if (RELU) v = fmaxf(v, 0.f);
                if (OUT_BF16)
                    ((unsigned short*)Cout)[(size_t)(rowb + r) * N + col] = f2bf(v);
                else
                    ((float*)Cout)[(size_t)(rowb + r) * N + col] = v;
            }
        }
    }
}

// ---------------------------------------------------------------------------
// QKV GEMM: A[8192,512] @ Wqkv[1536,512]^T + bias (gathered from bq/bk/bv).
// Cols [0,1024) -> QKb [8192][1024] (Q|K; Q pre-scaled by .125*log2e).
// Cols [1024,1536) -> VT [b][h][d=64][s=2048] bf16, packed ushort4 along s.
// ---------------------------------------------------------------------------
__global__ __launch_bounds__(256) void gemm_qkv(
    const unsigned short* __restrict__ A, const unsigned short* __restrict__ W,
    const float* __restrict__ bqp, const float* __restrict__ bkp,
    const float* __restrict__ bvp, unsigned short* __restrict__ QKb,
    unsigned short* __restrict__ VTg)
{
    constexpr int K = 512;
    __shared__ unsigned short Asl[128 * 64];
    __shared__ unsigned short Bsl[128 * 64];

    const int tid = threadIdx.x;
    const int w = tid >> 6, lane = tid & 63;
    const int lr = lane & 15, lg = lane >> 4;
    const int wm = w >> 1, wn = w & 1;
    const int flat = blockIdx.y * 12 + blockIdx.x;      // grid 12 x 64 = 768
    const int nf = (flat & 7) * 96 + (flat >> 3);
    const int m0 = (nf / 12) * 128, n0 = (nf % 12) * 128;
    const int srow = lane >> 3;
    const int schunk = lane & 7;

    f32x4 acc[4][4] = {};

    for (int k0 = 0; k0 < K; k0 += 64) {
        __syncthreads();
        #pragma unroll
        for (int j = 0; j < 4; ++j) {
            int instr = w * 4 + j;
            int row = instr * 8 + srow;
            gload16(A + (size_t)(m0 + row) * K + k0 + ((schunk ^ (row & 7)) * 8),
                    &Asl[instr * 512]);
            gload16(W + (size_t)(n0 + row) * K + k0 + ((schunk ^ (row & 7)) * 8),
                    &Bsl[instr * 512]);
        }
        __syncthreads();

        bf16x8 af[4][2], bfr[4][2];
        #pragma unroll
        for (int m = 0; m < 4; ++m)
            #pragma unroll
            for (int ko = 0; ko < 2; ++ko) {
                int row = wm * 64 + m * 16 + lr;
                int slot = (lg + 4 * ko) ^ (row & 7);
                af[m][ko] = *(const bf16x8*)&Asl[row * 64 + slot * 8];
            }
        #pragma unroll
        for (int n = 0; n < 4; ++n)
            #pragma unroll
            for (int ko = 0; ko < 2; ++ko) {
                int row = wn * 64 + n * 16 + lr;
                int slot = (lg + 4 * ko) ^ (row & 7);
                bfr[n][ko] = *(const bf16x8*)&Bsl[row * 64 + slot * 8];
            }
        #pragma unroll
        for (int m = 0; m < 4; ++m)
            #pragma unroll
            for (int n = 0; n < 4; ++n)
                #pragma unroll
                for (int ko = 0; ko < 2; ++ko)
                    acc[m][n] = mfma16(af[m][ko], bfr[n][ko], acc[m][n]);
    }

    if (n0 < 1024) {
        #pragma unroll
        for (int n = 0; n < 4; ++n) {
            int col = n0 + wn * 64 + n * 16 + lr;
            float bv = (col < 512) ? bqp[col] * (0.125f * LOG2E_) : bkp[col - 512];
            #pragma unroll
            for (int m = 0; m < 4; ++m) {
                int rowb = m0 + wm * 64 + m * 16 + lg * 4;
                #pragma unroll
                for (int r = 0; r < 4; ++r)
                    QKb[(size_t)(rowb + r) * 1024 + col] = f2bf(acc[m][n][r] + bv);
            }
        }
    } else {
        #pragma unroll
        for (int n = 0; n < 4; ++n) {
            int col = n0 + wn * 64 + n * 16 + lr;
            int dfull = col - 1024;
            int hh = dfull >> 6, dd = dfull & 63;
            float bv = bvp[dfull];
            #pragma unroll
            for (int m = 0; m < 4; ++m) {
                int rowb = m0 + wm * 64 + m * 16 + lg * 4;
                int bb = rowb >> 11;
                int s = rowb & 2047;
                ushort4 pk;
                pk.x = f2bf(acc[m][n][0] + bv);
                pk.y = f2bf(acc[m][n][1] + bv);
                pk.z = f2bf(acc[m][n][2] + bv);
                pk.w = f2bf(acc[m][n][3] + bv);
                *(ushort4*)&VTg[(((size_t)bb * 8 + hh) * 64 + dd) * 2048 + s] = pk;
            }
        }
    }
}

// ---------------------------------------------------------------------------
// MFMA flash attention v6 = r5 structure (single-buffer, proven 76.5us) +
// exp2-domain softmax (log2e folded into Q upstream) + mask bias as MFMA
// C-init (removes the post-QK^T add pass). QBLK=64, 1024 blocks, bijective
// XCD remap (KV L2-resident per XCD), defer-max (THR=8 in log2 units).
// ---------------------------------------------------------------------------
__global__ __launch_bounds__(256, 4) void attn_mfma5(
    const unsigned short* __restrict__ QKb, const unsigned short* __restrict__ VTg,
    const float* __restrict__ mb, unsigned short* __restrict__ Ob)
{
    __shared__ unsigned short Ks[64 * 64];     // [kv][d]  swizzled 16B chunks
    __shared__ unsigned short VTs[64 * 64];    // [d][kv]  swizzled 16B chunks
    __shared__ unsigned short Ps[4 * 16 * 64]; // per-wave [q][kv] swizzled
    __shared__ float Ms[64];

    const int tid = threadIdx.x;
    const int w = tid >> 6, lane = tid & 63;
    const int lr = lane & 15, lg = lane >> 4;
    const int flat = blockIdx.x + 32 * (blockIdx.y + 8 * blockIdx.z);
    const int nf = (flat & 7) * 128 + (flat >> 3);
    const int q0 = (nf & 31) * 64;
    const int bh = nf >> 5;
    const int h = bh & 7, b = bh >> 3;
    const int srow = lane >> 3;
    const int sc_x = (lane & 7) ^ srow;
    unsigned short* PsW = &Ps[w * 1024];

    // Q fragments (pre-scaled by 0.125*log2e upstream)
    bf16x8 qf[2];
    #pragma unroll
    for (int ko = 0; ko < 2; ++ko)
        qf[ko] = *(const bf16x8*)(QKb +
            (size_t)(b * S_ + q0 + w * 16 + lr) * 1024 + h * 64 + ko * 32 + lg * 8);

    f32x4 od[4] = {};
    float m_run = -INFINITY;   // log2 domain
    float l_run = 0.f;

    for (int kv0 = 0; kv0 < S_; kv0 += 64) {
        __syncthreads();
        #pragma unroll
        for (int j = 0; j < 2; ++j) {
            int rl = w * 16 + j * 8 + srow;
            gload16(QKb + (size_t)(b * S_ + kv0 + rl) * 1024 + 512 + h * 64 + sc_x * 8,
                    &Ks[(w * 2 + j) * 512]);
            gload16(VTg + ((size_t)bh * 64 + rl) * 2048 + kv0 + sc_x * 8,
                    &VTs[(w * 2 + j) * 512]);
        }
        if (w == 0) gload4(mb + (size_t)b * S_ + kv0 + lane, Ms);
        __syncthreads();

        // swapped QK^T with C initialized to the additive mask bias:
        // st[n] reg r = mask[kv] + S2[kv=16n+4lg+r][q=lr]  (log2-scaled)
        f32x4 st[4];
        #pragma unroll
        for (int n = 0; n < 4; ++n)
            st[n] = *(const f32x4*)&Ms[n * 16 + lg * 4];
        #pragma unroll
        for (int ko = 0; ko < 2; ++ko)
            #pragma unroll
            for (int n = 0; n < 4; ++n) {
                bf16x8 kf = *(const bf16x8*)
                    &Ks[(n * 16 + lr) * 64 + (((lg + 4 * ko) ^ (lr & 7)) * 8)];
                st[n] = mfma16(kf, qf[ko], st[n]);
            }

        float mtp = -INFINITY;
        #pragma unroll
        for (int n = 0; n < 4; ++n)
            #pragma unroll
            for (int r = 0; r < 4; ++r)
                mtp = fmaxf(mtp, st[n][r]);

        // defer-max: rescale only if partial max exceeds m_run + 8 (log2)
        if (__any(mtp > m_run + 8.f)) {
            float mt = mtp;
            mt = fmaxf(mt, __shfl_xor(mt, 16));
            mt = fmaxf(mt, __shfl_xor(mt, 32));
            float mnew = fmaxf(m_run, mt);
            float scl = exp2f(m_run - mnew);
            m_run = mnew;
            l_run *= scl;
            #pragma unroll
            for (int r = 0; r < 4; ++r) {
                float sr = __shfl(scl, lg * 4 + r);
                #pragma unroll
                for (int nd = 0; nd < 4; ++nd) od[nd][r] *= sr;
            }
        }

        float psum = 0.f;
        #pragma unroll
        for (int n = 0; n < 4; ++n) {
            float p0 = exp2f(st[n][0] - m_run);
            float p1 = exp2f(st[n][1] - m_run);
            float p2 = exp2f(st[n][2] - m_run);
            float p3 = exp2f(st[n][3] - m_run);
            psum += (p0 + p1) + (p2 + p3);
            ushort4 pk;
            pk.x = f2bf(p0); pk.y = f2bf(p1); pk.z = f2bf(p2); pk.w = f2bf(p3);
            int chunk = (2 * n + (lg >> 1)) ^ (lr & 7);
            *(ushort4*)&PsW[lr * 64 + chunk * 8 + (lg & 1) * 4] = pk;
        }
        psum += __shfl_xor(psum, 16);
        psum += __shfl_xor(psum, 32);
        l_run += psum;

        // PV: od[nd] += P[q][kv] * V^T[d][kv]
        #pragma unroll
        for (int ko = 0; ko < 2; ++ko) {
            int slotx = ((lg + 4 * ko) ^ (lr & 7)) * 8;
            bf16x8 pa = *(const bf16x8*)&PsW[lr * 64 + slotx];
            #pragma unroll
            for (int nd = 0; nd < 4; ++nd) {
                bf16x8 vf = *(const bf16x8*)&VTs[(nd * 16 + lr) * 64 + slotx];
                od[nd] = mfma16(pa, vf, od[nd]);
            }
        }
    }

    float linv = 1.f / l_run;
    #pragma unroll
    for (int r = 0; r < 4; ++r) {
        float iv = __shfl(linv, lg * 4 + r);
        size_t row = (size_t)(b * S_ + q0 + w * 16 + lg * 4 + r);
        #pragma unroll
        for (int nd = 0; nd < 4; ++nd)
            Ob[row * 512 + h * 64 + nd * 16 + lr] = f2bf(od[nd][r] * iv);
    }
}

// ---------------------------------------------------------------------------
// add+LN, one wave per row (4 rows/block), no __syncthreads.
// y = x + gamma*(a-mean)/sqrt(var_ddof1+eps) + beta ; optional bf16 copy.
// ---------------------------------------------------------------------------
__global__ __launch_bounds__(256) void add_ln2_kernel(
    const float* __restrict__ x, const float* __restrict__ a,
    const float* __restrict__ g, const float* __restrict__ beta,
    float* __restrict__ y, unsigned short* __restrict__ ybf)
{
    const int wv = threadIdx.x >> 6, lane = threadIdx.x & 63;
    const size_t row = (size_t)blockIdx.x * 4 + wv;
    const float4* a4 = (const float4*)(a + row * D_);
    float4 va0 = a4[lane * 2], va1 = a4[lane * 2 + 1];
    float s  = (va0.x + va0.y) + (va0.z + va0.w) + (va1.x + va1.y) + (va1.z + va1.w);
    float ss = (va0.x * va0.x + va0.y * va0.y) + (va0.z * va0.z + va0.w * va0.w)
             + (va1.x * va1.x + va1.y * va1.y) + (va1.z * va1.z + va1.w * va1.w);
    #pragma unroll
    for (int off = 32; off > 0; off >>= 1) {
        s  += __shfl_xor(s, off);
        ss += __shfl_xor(ss, off);
    }
    float mean = s * (1.f / (float)D_);
    float var  = (ss - (float)D_ * mean * mean) * (1.f / (float)(D_ - 1));
    float rstd = rsqrtf(var + EPS_);
    float gg = g[0], bb = beta[0];
    const float4* x4 = (const float4*)(x + row * D_);
    float4 vx0 = x4[lane * 2], vx1 = x4[lane * 2 + 1];
    float4 o0, o1;
    o0.x = vx0.x + gg * (va0.x - mean) * rstd + bb;
    o0.y = vx0.y + gg * (va0.y - mean) * rstd + bb;
    o0.z = vx0.z + gg * (va0.z - mean) * rstd + bb;
    o0.w = vx0.w + gg * (va0.w - mean) * rstd + bb;
    o1.x = vx1.x + gg * (va1.x - mean) * rstd + bb;
    o1.y = vx1.y + gg * (va1.y - mean) * rstd + bb;
    o1.z = vx1.z + gg * (va1.z - mean) * rstd + bb;
    o1.w = vx1.w + gg * (va1.w - mean) * rstd + bb;
    ((float4*)(y + row * D_))[lane * 2]     = o0;
    ((float4*)(y + row * D_))[lane * 2 + 1] = o1;
    if (ybf) {
        ushort4 u0, u1;
        u0.x = f2bf(o0.x); u0.y = f2bf(o0.y); u0.z = f2bf(o0.z); u0.w = f2bf(o0.w);
        u1.x = f2bf(o1.x); u1.y = f2bf(o1.y); u1.z = f2bf(o1.z); u1.w = f2bf(o1.w);
        ((ushort4*)(ybf + row * D_))[lane * 2]     = u0;
        ((ushort4*)(ybf + row * D_))[lane * 2 + 1] = u1;
    }
}

// ---------------------------------------------------------------------------
extern "C" void kernel_launch(void* const* d_in, const int* in_sizes, int n_in,
                              void* d_out, int out_size, void* d_ws, size_t ws_size,
                              hipStream_t stream) {
    const float* x  = (const float*)d_in[0];
    const unsigned char* mask = (const unsigned char*)d_in[1];
    const float* wq = (const float*)d_in[2];
    const float* bq = (const float*)d_in[3];
    const float* wk = (const float*)d_in[4];
    const float* bk = (const float*)d_in[5];
    const float* wv = (const float*)d_in[6];
    const float* bv = (const float*)d_in[7];
    const float* wo = (const float*)d_in[8];
    const float* bo = (const float*)d_in[9];
    const float* w1 = (const float*)d_in[10];
    const float* b1 = (const float*)d_in[11];
    const float* w2 = (const float*)d_in[12];
    const float* b2 = (const float*)d_in[13];
    const float* g1 = (const float*)d_in[14];
    const float* be1 = (const float*)d_in[15];
    const float* g2 = (const float*)d_in[16];
    const float* be2 = (const float*)d_in[17];
    float* out = (float*)d_out;
    char* base = (char*)d_ws;

    const size_t MS = (size_t)B_ * S_;                              // 8192
    unsigned short* QKb  = (unsigned short*)(base);                 // 16 MB
    unsigned short* VTg  = (unsigned short*)(base + 16777216);      // 8 MB
    unsigned short* Ob   = (unsigned short*)(base + 25165824);      // 8 MB
    unsigned short* ff1  = (unsigned short*)(base);                 // 32 MB overlay
    float*          att  = (float*)(base + 33554432);               // 16 MB
    float*          ff2  = att;                                     // overlay
    float*          y    = (float*)(base + 50331648);               // 16 MB
    unsigned short* ybf  = (unsigned short*)(base + 67108864);      // 8 MB
    unsigned short* xb   = (unsigned short*)(base + 75497472);      // 8 MB
    unsigned short* wqkvb= (unsigned short*)(base + 83886080);      // 1.5 MB
    unsigned short* wob  = (unsigned short*)(base + 85458944);      // 0.5 MB
    unsigned short* w1b  = (unsigned short*)(base + 85983232);      // 2 MB
    unsigned short* w2b  = (unsigned short*)(base + 88080384);      // 2 MB
    float*          mbv  = (float*)(base + 90183680);               // 32 KB

    dim3 blk(256);
    prep_kernel<<<7176, blk, 0, stream>>>(
        mask, mbv, x, wq, wk, wv, wo, w1, w2, xb, wqkvb, wob, w1b, w2b);

    // fused QKV projection; Q pre-scaled, V written transposed per-head
    gemm_qkv<<<dim3(12, MS / 128), blk, 0, stream>>>(
        xb, wqkvb, bq, bk, bv, QKb, VTg);

    attn_mfma5<<<dim3(S_ / 64, H_, B_), blk, 0, stream>>>(QKb, VTg, mbv, Ob);

    gemm_mfma<128,64,false,false><<<dim3(D_/64, MS/128), blk, 0, stream>>>(
        Ob, wob, bo, att, MS, D_, D_);

    add_ln2_kernel<<<dim3((unsigned)(MS / 4)), blk, 0, stream>>>(x, att, g1, be1, y, ybf);

    gemm_mfma<128,128,true,true><<<dim3(DFF_/128, MS/128), blk, 0, stream>>>(
        ybf, w1b, b1, ff1, MS, DFF_, D_);
    gemm_mfma<128,64,false,false><<<dim3(D_/64, MS/128), blk, 0, stream>>>(
        ff1, w2b, b2, ff2, MS, D_, DFF_);

    add_ln2_kernel<<<dim3((unsigned)(MS / 4)), blk, 0, stream>>>(y, ff2, g2, be2, out, nullptr);
}

// Round 10
// 276.969 us; speedup vs baseline: 1.0844x; 1.0690x over previous
//
#include <hip/hip_runtime.h>
#include <hip/hip_bf16.h>
#include <math.h>

#define B_ 4
#define S_ 2048
#define D_ 512
#define H_ 8
#define DK_ 64
#define DFF_ 2048
#define NEG_ (-1.0e9f)
#define EPS_ 1e-6f

typedef __attribute__((ext_vector_type(8))) short bf16x8;
typedef __attribute__((ext_vector_type(4))) float f32x4;

__device__ inline unsigned short f2bf(float f) {
    unsigned u = __float_as_uint(f);
    unsigned r = u + 0x7FFFu + ((u >> 16) & 1u);
    return (unsigned short)(r >> 16);
}

__device__ inline f32x4 mfma16(bf16x8 a, bf16x8 b, f32x4 c) {
    return __builtin_amdgcn_mfma_f32_16x16x32_bf16(a, b, c, 0, 0, 0);
}

// global -> LDS direct. LDS dest = wave-uniform base + lane*size.
__device__ inline void gload16(const void* g, void* l) {
    __builtin_amdgcn_global_load_lds(
        (const __attribute__((address_space(1))) unsigned int*)g,
        (__attribute__((address_space(3))) unsigned int*)l, 16, 0, 0);
}
__device__ inline void gload4(const void* g, void* l) {
    __builtin_amdgcn_global_load_lds(
        (const __attribute__((address_space(1))) unsigned int*)g,
        (__attribute__((address_space(3))) unsigned int*)l, 4, 0, 0);
}

// ---------------------------------------------------------------------------
// Merged: blocks 0..7 canonicalize mask -> additive f32 bias (0 or NEG);
// blocks 8.. convert x + weights f32->bf16 (wq scale folded: 0.125).
// ---------------------------------------------------------------------------
__global__ __launch_bounds__(256) void prep_kernel(
    const unsigned char* __restrict__ mraw, float* __restrict__ mb,
    const float* __restrict__ x,  const float* __restrict__ wq,
    const float* __restrict__ wk, const float* __restrict__ wv,
    const float* __restrict__ wo, const float* __restrict__ w1,
    const float* __restrict__ w2,
    unsigned short* __restrict__ xb, unsigned short* __restrict__ wqkvb,
    unsigned short* __restrict__ wob, unsigned short* __restrict__ w1b,
    unsigned short* __restrict__ w2b)
{
    int tid = threadIdx.x;
    if (blockIdx.x < 8) {
        __shared__ int s_bad;
        if (tid == 0) s_bad = 0;
        __syncthreads();
        const unsigned int* w = (const unsigned int*)mraw;
        int bad = 0;
        for (int i = tid; i < (B_ * S_) / 4; i += 256) {
            unsigned int v = w[i];
            if (!(v == 0u || v == 1u || v == 0x3F800000u)) bad = 1;
        }
        if (bad) atomicOr(&s_bad, 1);
        __syncthreads();
        int i = blockIdx.x * 256 + tid;
        if (s_bad) {  // u8 layout
            for (; i < B_ * S_; i += 2048) mb[i] = mraw[i] ? NEG_ : 0.f;
        } else {      // 4-byte layout
            for (; i < B_ * S_; i += 2048) mb[i] = w[i] ? NEG_ : 0.f;
        }
        return;
    }
    int i = (blockIdx.x - 8) * 256 + tid;   // float4 index, total 1835008
    const float* src; unsigned short* dst; int off; float s = 1.f;
    if (i < 1048576)      { src = x;  dst = xb;             off = i;           }
    else if (i < 1114112) { src = wq; dst = wqkvb;          off = i - 1048576; s = 0.125f; }
    else if (i < 1179648) { src = wk; dst = wqkvb + 262144; off = i - 1114112; }
    else if (i < 1245184) { src = wv; dst = wqkvb + 524288; off = i - 1179648; }
    else if (i < 1310720) { src = wo; dst = wob;            off = i - 1245184; }
    else if (i < 1572864) { src = w1; dst = w1b;            off = i - 1310720; }
    else                  { src = w2; dst = w2b;            off = i - 1572864; }
    float4 v = reinterpret_cast<const float4*>(src)[off];
    ushort4 o;
    o.x = f2bf(v.x * s); o.y = f2bf(v.y * s); o.z = f2bf(v.z * s); o.w = f2bf(v.w * s);
    reinterpret_cast<ushort4*>(dst)[off] = o;
}

// ---------------------------------------------------------------------------
// Generic MFMA GEMM: C[M,N] = A[M,K](bf16) @ W[N,K](bf16)^T + bias(f32)
// XCD-aware bijective block remap (grids are multiples of 8).
// ---------------------------------------------------------------------------
template<int BM, int BN, bool RELU, bool OUT_BF16>
__global__ __launch_bounds__(256) void gemm_mfma(
    const unsigned short* __restrict__ A, const unsigned short* __restrict__ W,
    const float* __restrict__ bias, void* __restrict__ Cout,
    int M, int N, int K)
{
    constexpr int FM = BM / 32;
    constexpr int FN = BN / 32;
    __shared__ unsigned short Asl[BM * 64];
    __shared__ unsigned short Bsl[BN * 64];

    const int tid = threadIdx.x;
    const int w = tid >> 6, lane = tid & 63;
    const int lr = lane & 15, lg = lane >> 4;
    const int wm = w >> 1, wn = w & 1;
    const int gx = gridDim.x;
    const int flat = blockIdx.y * gx + blockIdx.x;
    const int cpx = (gx * gridDim.y) >> 3;
    const int nf = (flat & 7) * cpx + (flat >> 3);
    const int m0 = (nf / gx) * BM, n0 = (nf % gx) * BN;
    const int srow = lane >> 3;
    const int schunk = lane & 7;

    f32x4 acc[FM][FN] = {};

    for (int k0 = 0; k0 < K; k0 += 64) {
        __syncthreads();
        #pragma unroll
        for (int j = 0; j < BM / 32; ++j) {
            int instr = w * (BM / 32) + j;
            int row = instr * 8 + srow;
            const unsigned short* src =
                A + (size_t)(m0 + row) * K + k0 + ((schunk ^ (row & 7)) * 8);
            gload16(src, &Asl[instr * 512]);
        }
        #pragma unroll
        for (int j = 0; j < BN / 32; ++j) {
            int instr = w * (BN / 32) + j;
            int row = instr * 8 + srow;
            const unsigned short* src =
                W + (size_t)(n0 + row) * K + k0 + ((schunk ^ (row & 7)) * 8);
            gload16(src, &Bsl[instr * 512]);
        }
        __syncthreads();

        bf16x8 af[FM][2], bfr[FN][2];
        #pragma unroll
        for (int m = 0; m < FM; ++m)
            #pragma unroll
            for (int ko = 0; ko < 2; ++ko) {
                int row = wm * (FM * 16) + m * 16 + lr;
                int slot = (lg + 4 * ko) ^ (row & 7);
                af[m][ko] = *(const bf16x8*)&Asl[row * 64 + slot * 8];
            }
        #pragma unroll
        for (int n = 0; n < FN; ++n)
            #pragma unroll
            for (int ko = 0; ko < 2; ++ko) {
                int row = wn * (FN * 16) + n * 16 + lr;
                int slot = (lg + 4 * ko) ^ (row & 7);
                bfr[n][ko] = *(const bf16x8*)&Bsl[row * 64 + slot * 8];
            }
        #pragma unroll
        for (int m = 0; m < FM; ++m)
            #pragma unroll
            for (int n = 0; n < FN; ++n)
                #pragma unroll
                for (int ko = 0; ko < 2; ++ko)
                    acc[m][n] = mfma16(af[m][ko], bfr[n][ko], acc[m][n]);
    }

    #pragma unroll
    for (int n = 0; n < FN; ++n) {
        int col = n0 + wn * (FN * 16) + n * 16 + lr;
        float bv = bias[col];
        #pragma unroll
        for (int m = 0; m < FM; ++m) {
            int rowb = m0 + wm * (FM * 16) + m * 16 + lg * 4;
            #pragma unroll
            for (int r = 0; r < 4; ++r) {
                float v = acc[m][n][r] + bv;
                if (RELU) v = fmaxf(v, 0.f);
                if (OUT_BF16)
                    ((unsigned short*)Cout)[(size_t)(rowb + r) * N + col] = f2bf(v);
                else
                    ((float*)Cout)[(size_t)(rowb + r) * N + col] = v;
            }
        }
    }
}

// ---------------------------------------------------------------------------
// QKV GEMM: A[8192,512] @ Wqkv[1536,512]^T + bias (gathered from bq/bk/bv).
// Cols [0,1024) -> QKb [8192][1024] (Q|K; Q pre-scaled by 0.125).
// Cols [1024,1536) -> VT [b][h][d=64][s=2048] bf16, packed ushort4 along s.
// ---------------------------------------------------------------------------
__global__ __launch_bounds__(256) void gemm_qkv(
    const unsigned short* __restrict__ A, const unsigned short* __restrict__ W,
    const float* __restrict__ bqp, const float* __restrict__ bkp,
    const float* __restrict__ bvp, unsigned short* __restrict__ QKb,
    unsigned short* __restrict__ VTg)
{
    constexpr int K = 512;
    __shared__ unsigned short Asl[128 * 64];
    __shared__ unsigned short Bsl[128 * 64];

    const int tid = threadIdx.x;
    const int w = tid >> 6, lane = tid & 63;
    const int lr = lane & 15, lg = lane >> 4;
    const int wm = w >> 1, wn = w & 1;
    const int flat = blockIdx.y * 12 + blockIdx.x;      // grid 12 x 64 = 768
    const int nf = (flat & 7) * 96 + (flat >> 3);
    const int m0 = (nf / 12) * 128, n0 = (nf % 12) * 128;
    const int srow = lane >> 3;
    const int schunk = lane & 7;

    f32x4 acc[4][4] = {};

    for (int k0 = 0; k0 < K; k0 += 64) {
        __syncthreads();
        #pragma unroll
        for (int j = 0; j < 4; ++j) {
            int instr = w * 4 + j;
            int row = instr * 8 + srow;
            gload16(A + (size_t)(m0 + row) * K + k0 + ((schunk ^ (row & 7)) * 8),
                    &Asl[instr * 512]);
            gload16(W + (size_t)(n0 + row) * K + k0 + ((schunk ^ (row & 7)) * 8),
                    &Bsl[instr * 512]);
        }
        __syncthreads();

        bf16x8 af[4][2], bfr[4][2];
        #pragma unroll
        for (int m = 0; m < 4; ++m)
            #pragma unroll
            for (int ko = 0; ko < 2; ++ko) {
                int row = wm * 64 + m * 16 + lr;
                int slot = (lg + 4 * ko) ^ (row & 7);
                af[m][ko] = *(const bf16x8*)&Asl[row * 64 + slot * 8];
            }
        #pragma unroll
        for (int n = 0; n < 4; ++n)
            #pragma unroll
            for (int ko = 0; ko < 2; ++ko) {
                int row = wn * 64 + n * 16 + lr;
                int slot = (lg + 4 * ko) ^ (row & 7);
                bfr[n][ko] = *(const bf16x8*)&Bsl[row * 64 + slot * 8];
            }
        #pragma unroll
        for (int m = 0; m < 4; ++m)
            #pragma unroll
            for (int n = 0; n < 4; ++n)
                #pragma unroll
                for (int ko = 0; ko < 2; ++ko)
                    acc[m][n] = mfma16(af[m][ko], bfr[n][ko], acc[m][n]);
    }

    if (n0 < 1024) {
        #pragma unroll
        for (int n = 0; n < 4; ++n) {
            int col = n0 + wn * 64 + n * 16 + lr;
            float bv = (col < 512) ? bqp[col] * 0.125f : bkp[col - 512];
            #pragma unroll
            for (int m = 0; m < 4; ++m) {
                int rowb = m0 + wm * 64 + m * 16 + lg * 4;
                #pragma unroll
                for (int r = 0; r < 4; ++r)
                    QKb[(size_t)(rowb + r) * 1024 + col] = f2bf(acc[m][n][r] + bv);
            }
        }
    } else {
        #pragma unroll
        for (int n = 0; n < 4; ++n) {
            int col = n0 + wn * 64 + n * 16 + lr;
            int dfull = col - 1024;
            int hh = dfull >> 6, dd = dfull & 63;
            float bv = bvp[dfull];
            #pragma unroll
            for (int m = 0; m < 4; ++m) {
                int rowb = m0 + wm * 64 + m * 16 + lg * 4;
                int bb = rowb >> 11;
                int s = rowb & 2047;
                ushort4 pk;
                pk.x = f2bf(acc[m][n][0] + bv);
                pk.y = f2bf(acc[m][n][1] + bv);
                pk.z = f2bf(acc[m][n][2] + bv);
                pk.w = f2bf(acc[m][n][3] + bv);
                *(ushort4*)&VTg[(((size_t)bb * 8 + hh) * 64 + dd) * 2048 + s] = pk;
            }
        }
    }
}

// ---------------------------------------------------------------------------
// MFMA flash attention v8 = r5 structure (passed, 76.5us: single buffer,
// __expf natural domain, f2bf ushort4 P-store) + mask-as-MFMA-C-init (r7
// proven) + nested-fmax tile max (fuses to v_max3). QBLK=64, 1024 blocks,
// bijective XCD remap, defer-max THR=4.
// ---------------------------------------------------------------------------
__global__ __launch_bounds__(256, 4) void attn_mfma7(
    const unsigned short* __restrict__ QKb, const unsigned short* __restrict__ VTg,
    const float* __restrict__ mb, unsigned short* __restrict__ Ob)
{
    __shared__ unsigned short Ks[64 * 64];     // [kv][d]  swizzled 16B chunks
    __shared__ unsigned short VTs[64 * 64];    // [d][kv]  swizzled 16B chunks
    __shared__ unsigned short Ps[4 * 16 * 64]; // per-wave [q][kv] swizzled
    __shared__ float Ms[64];

    const int tid = threadIdx.x;
    const int w = tid >> 6, lane = tid & 63;
    const int lr = lane & 15, lg = lane >> 4;
    const int flat = blockIdx.x + 32 * (blockIdx.y + 8 * blockIdx.z);
    const int nf = (flat & 7) * 128 + (flat >> 3);
    const int q0 = (nf & 31) * 64;
    const int bh = nf >> 5;
    const int h = bh & 7, b = bh >> 3;
    const int srow = lane >> 3;
    const int sc_x = (lane & 7) ^ srow;
    unsigned short* PsW = &Ps[w * 1024];

    // Q fragments (pre-scaled by 0.125 upstream)
    bf16x8 qf[2];
    #pragma unroll
    for (int ko = 0; ko < 2; ++ko)
        qf[ko] = *(const bf16x8*)(QKb +
            (size_t)(b * S_ + q0 + w * 16 + lr) * 1024 + h * 64 + ko * 32 + lg * 8);

    f32x4 od[4] = {};
    float m_run = -INFINITY;
    float l_run = 0.f;

    for (int kv0 = 0; kv0 < S_; kv0 += 64) {
        __syncthreads();
        #pragma unroll
        for (int j = 0; j < 2; ++j) {
            int rl = w * 16 + j * 8 + srow;
            gload16(QKb + (size_t)(b * S_ + kv0 + rl) * 1024 + 512 + h * 64 + sc_x * 8,
                    &Ks[(w * 2 + j) * 512]);
            gload16(VTg + ((size_t)bh * 64 + rl) * 2048 + kv0 + sc_x * 8,
                    &VTs[(w * 2 + j) * 512]);
        }
        if (w == 0) gload4(mb + (size_t)b * S_ + kv0 + lane, Ms);
        __syncthreads();

        // swapped QK^T, C init = additive mask bias:
        // st[n] reg r = mask[kv] + S[kv=16n+4lg+r][q=lr]   (Q pre-scaled)
        f32x4 st[4];
        #pragma unroll
        for (int n = 0; n < 4; ++n)
            st[n] = *(const f32x4*)&Ms[n * 16 + lg * 4];
        #pragma unroll
        for (int ko = 0; ko < 2; ++ko)
            #pragma unroll
            for (int n = 0; n < 4; ++n) {
                bf16x8 kf = *(const bf16x8*)
                    &Ks[(n * 16 + lr) * 64 + (((lg + 4 * ko) ^ (lr & 7)) * 8)];
                st[n] = mfma16(kf, qf[ko], st[n]);
            }

        // per-lane tile max (nested fmax -> v_max3 fusion)
        float mtp = fmaxf(fmaxf(st[0][0], st[0][1]), st[0][2]);
        mtp = fmaxf(fmaxf(mtp, st[0][3]), st[1][0]);
        mtp = fmaxf(fmaxf(mtp, st[1][1]), st[1][2]);
        mtp = fmaxf(fmaxf(mtp, st[1][3]), st[2][0]);
        mtp = fmaxf(fmaxf(mtp, st[2][1]), st[2][2]);
        mtp = fmaxf(fmaxf(mtp, st[2][3]), st[3][0]);
        mtp = fmaxf(fmaxf(mtp, st[3][1]), st[3][2]);
        mtp = fmaxf(mtp, st[3][3]);

        // defer-max: rescale only if partial max exceeds m_run + 4
        if (__any(mtp > m_run + 4.f)) {
            float mt = mtp;
            mt = fmaxf(mt, __shfl_xor(mt, 16));
            mt = fmaxf(mt, __shfl_xor(mt, 32));
            float mnew = fmaxf(m_run, mt);
            float scl = __expf(m_run - mnew);
            m_run = mnew;
            l_run *= scl;
            #pragma unroll
            for (int r = 0; r < 4; ++r) {
                float sr = __shfl(scl, lg * 4 + r);
                #pragma unroll
                for (int nd = 0; nd < 4; ++nd) od[nd][r] *= sr;
            }
        }

        float psum = 0.f;
        #pragma unroll
        for (int n = 0; n < 4; ++n) {
            float p0 = __expf(st[n][0] - m_run);
            float p1 = __expf(st[n][1] - m_run);
            float p2 = __expf(st[n][2] - m_run);
            float p3 = __expf(st[n][3] - m_run);
            psum += (p0 + p1) + (p2 + p3);
            ushort4 pk;
            pk.x = f2bf(p0); pk.y = f2bf(p1); pk.z = f2bf(p2); pk.w = f2bf(p3);
            int chunk = (2 * n + (lg >> 1)) ^ (lr & 7);
            *(ushort4*)&PsW[lr * 64 + chunk * 8 + (lg & 1) * 4] = pk;
        }
        psum += __shfl_xor(psum, 16);
        psum += __shfl_xor(psum, 32);
        l_run += psum;

        // PV: od[nd] += P[q][kv] * V^T[d][kv]
        #pragma unroll
        for (int ko = 0; ko < 2; ++ko) {
            int slotx = ((lg + 4 * ko) ^ (lr & 7)) * 8;
            bf16x8 pa = *(const bf16x8*)&PsW[lr * 64 + slotx];
            #pragma unroll
            for (int nd = 0; nd < 4; ++nd) {
                bf16x8 vf = *(const bf16x8*)&VTs[(nd * 16 + lr) * 64 + slotx];
                od[nd] = mfma16(pa, vf, od[nd]);
            }
        }
    }

    float linv = 1.f / l_run;
    #pragma unroll
    for (int r = 0; r < 4; ++r) {
        float iv = __shfl(linv, lg * 4 + r);
        size_t row = (size_t)(b * S_ + q0 + w * 16 + lg * 4 + r);
        #pragma unroll
        for (int nd = 0; nd < 4; ++nd)
            Ob[row * 512 + h * 64 + nd * 16 + lr] = f2bf(od[nd][r] * iv);
    }
}

// ---------------------------------------------------------------------------
// add+LN, one wave per row (4 rows/block), no __syncthreads.
// y = x + gamma*(a-mean)/sqrt(var_ddof1+eps) + beta ; optional bf16 copy.
// ---------------------------------------------------------------------------
__global__ __launch_bounds__(256) void add_ln2_kernel(
    const float* __restrict__ x, const float* __restrict__ a,
    const float* __restrict__ g, const float* __restrict__ beta,
    float* __restrict__ y, unsigned short* __restrict__ ybf)
{
    const int wv = threadIdx.x >> 6, lane = threadIdx.x & 63;
    const size_t row = (size_t)blockIdx.x * 4 + wv;
    const float4* a4 = (const float4*)(a + row * D_);
    float4 va0 = a4[lane * 2], va1 = a4[lane * 2 + 1];
    float s  = (va0.x + va0.y) + (va0.z + va0.w) + (va1.x + va1.y) + (va1.z + va1.w);
    float ss = (va0.x * va0.x + va0.y * va0.y) + (va0.z * va0.z + va0.w * va0.w)
             + (va1.x * va1.x + va1.y * va1.y) + (va1.z * va1.z + va1.w * va1.w);
    #pragma unroll
    for (int off = 32; off > 0; off >>= 1) {
        s  += __shfl_xor(s, off);
        ss += __shfl_xor(ss, off);
    }
    float mean = s * (1.f / (float)D_);
    float var  = (ss - (float)D_ * mean * mean) * (1.f / (float)(D_ - 1));
    float rstd = rsqrtf(var + EPS_);
    float gg = g[0], bb = beta[0];
    const float4* x4 = (const float4*)(x + row * D_);
    float4 vx0 = x4[lane * 2], vx1 = x4[lane * 2 + 1];
    float4 o0, o1;
    o0.x = vx0.x + gg * (va0.x - mean) * rstd + bb;
    o0.y = vx0.y + gg * (va0.y - mean) * rstd + bb;
    o0.z = vx0.z + gg * (va0.z - mean) * rstd + bb;
    o0.w = vx0.w + gg * (va0.w - mean) * rstd + bb;
    o1.x = vx1.x + gg * (va1.x - mean) * rstd + bb;
    o1.y = vx1.y + gg * (va1.y - mean) * rstd + bb;
    o1.z = vx1.z + gg * (va1.z - mean) * rstd + bb;
    o1.w = vx1.w + gg * (va1.w - mean) * rstd + bb;
    ((float4*)(y + row * D_))[lane * 2]     = o0;
    ((float4*)(y + row * D_))[lane * 2 + 1] = o1;
    if (ybf) {
        ushort4 u0, u1;
        u0.x = f2bf(o0.x); u0.y = f2bf(o0.y); u0.z = f2bf(o0.z); u0.w = f2bf(o0.w);
        u1.x = f2bf(o1.x); u1.y = f2bf(o1.y); u1.z = f2bf(o1.z); u1.w = f2bf(o1.w);
        ((ushort4*)(ybf + row * D_))[lane * 2]     = u0;
        ((ushort4*)(ybf + row * D_))[lane * 2 + 1] = u1;
    }
}

// ---------------------------------------------------------------------------
extern "C" void kernel_launch(void* const* d_in, const int* in_sizes, int n_in,
                              void* d_out, int out_size, void* d_ws, size_t ws_size,
                              hipStream_t stream) {
    const float* x  = (const float*)d_in[0];
    const unsigned char* mask = (const unsigned char*)d_in[1];
    const float* wq = (const float*)d_in[2];
    const float* bq = (const float*)d_in[3];
    const float* wk = (const float*)d_in[4];
    const float* bk = (const float*)d_in[5];
    const float* wv = (const float*)d_in[6];
    const float* bv = (const float*)d_in[7];
    const float* wo = (const float*)d_in[8];
    const float* bo = (const float*)d_in[9];
    const float* w1 = (const float*)d_in[10];
    const float* b1 = (const float*)d_in[11];
    const float* w2 = (const float*)d_in[12];
    const float* b2 = (const float*)d_in[13];
    const float* g1 = (const float*)d_in[14];
    const float* be1 = (const float*)d_in[15];
    const float* g2 = (const float*)d_in[16];
    const float* be2 = (const float*)d_in[17];
    float* out = (float*)d_out;
    char* base = (char*)d_ws;

    const size_t MS = (size_t)B_ * S_;                              // 8192
    unsigned short* QKb  = (unsigned short*)(base);                 // 16 MB
    unsigned short* VTg  = (unsigned short*)(base + 16777216);      // 8 MB
    unsigned short* Ob   = (unsigned short*)(base + 25165824);      // 8 MB
    unsigned short* ff1  = (unsigned short*)(base);                 // 32 MB overlay
    float*          att  = (float*)(base + 33554432);               // 16 MB
    float*          ff2  = att;                                     // overlay
    float*          y    = (float*)(base + 50331648);               // 16 MB
    unsigned short* ybf  = (unsigned short*)(base + 67108864);      // 8 MB
    unsigned short* xb   = (unsigned short*)(base + 75497472);      // 8 MB
    unsigned short* wqkvb= (unsigned short*)(base + 83886080);      // 1.5 MB
    unsigned short* wob  = (unsigned short*)(base + 85458944);      // 0.5 MB
    unsigned short* w1b  = (unsigned short*)(base + 85983232);      // 2 MB
    unsigned short* w2b  = (unsigned short*)(base + 88080384);      // 2 MB
    float*          mbv  = (float*)(base + 90183680);               // 32 KB

    dim3 blk(256);
    prep_kernel<<<7176, blk, 0, stream>>>(
        mask, mbv, x, wq, wk, wv, wo, w1, w2, xb, wqkvb, wob, w1b, w2b);

    // fused QKV projection; Q pre-scaled, V written transposed per-head
    gemm_qkv<<<dim3(12, MS / 128), blk, 0, stream>>>(
        xb, wqkvb, bq, bk, bv, QKb, VTg);

    attn_mfma7<<<dim3(S_ / 64, H_, B_), blk, 0, stream>>>(QKb, VTg, mbv, Ob);

    gemm_mfma<128,64,false,false><<<dim3(D_/64, MS/128), blk, 0, stream>>>(
        Ob, wob, bo, att, MS, D_, D_);

    add_ln2_kernel<<<dim3((unsigned)(MS / 4)), blk, 0, stream>>>(x, att, g1, be1, y, ybf);

    gemm_mfma<128,128,true,true><<<dim3(DFF_/128, MS/128), blk, 0, stream>>>(
        ybf, w1b, b1, ff1, MS, DFF_, D_);
    gemm_mfma<128,64,false,false><<<dim3(D_/64, MS/128), blk, 0, stream>>>(
        ff1, w2b, b2, ff2, MS, D_, DFF_);

    add_ln2_kernel<<<dim3((unsigned)(MS / 4)), blk, 0, stream>>>(y, ff2, g2, be2, out, nullptr);
}